// Round 2
// baseline (2052.461 us; speedup 1.0000x reference)
//
#include <hip/hip_runtime.h>
#include <stdint.h>

#define AS1 __attribute__((address_space(1)))
#define AS3 __attribute__((address_space(3)))

typedef unsigned short US;
typedef __bf16 bf16x8 __attribute__((ext_vector_type(8)));
typedef float f32x4 __attribute__((ext_vector_type(4)));

static constexpr int Bsz = 16384;
static constexpr int DIN = 512;
static constexpr int DH  = 1024;
static constexpr int LDA = 2560;   // Ab row: [h(1024) | x(512) | s(1024)]

__device__ __forceinline__ US f2bf(float f) {
  unsigned u = __float_as_uint(f);
  u += 0x7fffu + ((u >> 16) & 1u);          // RNE
  return (US)(u >> 16);
}
__device__ __forceinline__ float bf2f(US u) { return __uint_as_float(((unsigned)u) << 16); }
__device__ __forceinline__ float sigm(float x) { return 1.f / (1.f + __expf(-x)); }
__device__ __forceinline__ float tanh_f(float x) { return 1.f - 2.f / (1.f + __expf(2.f * x)); }

// ---------- convert kernels ----------
__global__ void pack_A(const float* __restrict__ h, const float* __restrict__ x,
                       US* __restrict__ Ab) {
  const int total = Bsz * 384;              // 1536 cols / 4 per item
  for (int idx = blockIdx.x * blockDim.x + threadIdx.x; idx < total;
       idx += gridDim.x * blockDim.x) {
    int row = idx / 384;
    int c = (idx - row * 384) * 4;
    const float* src = (c < DH) ? (h + (size_t)row * DH + c)
                                : (x + (size_t)row * DIN + (c - DH));
    float4 v = *(const float4*)src;
    ushort4 o;
    o.x = f2bf(v.x); o.y = f2bf(v.y); o.z = f2bf(v.z); o.w = f2bf(v.w);
    *(ushort4*)(Ab + (size_t)row * LDA + c) = o;
  }
}

struct WSlot { const float* src; US* dst; int n4; };
struct WBatch { WSlot s[11]; };
__global__ void conv_w(WBatch b) {
  WSlot sl = b.s[blockIdx.y];
  for (int i = blockIdx.x * blockDim.x + threadIdx.x; i < sl.n4;
       i += gridDim.x * blockDim.x) {
    float4 v = *(const float4*)(sl.src + (size_t)i * 4);
    ushort4 o;
    o.x = f2bf(v.x); o.y = f2bf(v.y); o.z = f2bf(v.z); o.w = f2bf(v.w);
    *(ushort4*)(sl.dst + (size_t)i * 4) = o;
  }
}

// ---------- segmented-K GEMM, C = A @ W^T, fused epilogue ----------
// epi: 0=s(tanh,+delta*Wst, ->Ab s-slot bf16)  1=r(sigm*h ->RH bf16)
//      2=z(sigm ->Z bf16)  3=htilde(tanh ->HT bf16)
//      4=T(sigm; h_t=(1-z)(T*h)+z*ht ->f32 out)
struct GateP {
  const US* W0; const US* W1; const US* W2;
  const float* bias;
  const void* aux0; const void* aux1; const void* aux2;
  void* outp;
  int ldo; int epi;
};
struct GateBatch { GateP g[3]; };

__global__ __launch_bounds__(256) void gemm_ep(
    const US* __restrict__ A0, int lda0, int kt0,
    const US* __restrict__ A1, int lda1, int kt1,
    const US* __restrict__ A2, int lda2, int kt2,
    int ldw0, int ldw1, int ldw2,
    GateBatch gb) {
  __shared__ __align__(16) US As[128 * 64];
  __shared__ __align__(16) US Bs[128 * 64];

  const GateP g = gb.g[blockIdx.z];

  const int tid  = threadIdx.x;
  const int lane = tid & 63;
  const int w    = tid >> 6;
  const int mBase = blockIdx.y * 128;
  const int nBase = blockIdx.x * 128;

  f32x4 acc[4][4];
#pragma unroll
  for (int i = 0; i < 4; i++)
#pragma unroll
    for (int j = 0; j < 4; j++) acc[i][j] = f32x4{0.f, 0.f, 0.f, 0.f};

  // staging: lane covers row rowL (rel), chunk cc (16B chunks of 8 bf16);
  // XOR-swizzle: LDS(m, cc) holds global(m, cc ^ (m&7))
  const int rowL = w * 32 + (lane >> 3);
  const int cc   = lane & 7;
  const int scc  = cc ^ ((lane >> 3) & 7);       // swizzled global chunk
  const int gOff = scc * 8;                       // element offset in row
  const int wm = (w & 1) * 64, wn = (w >> 1) * 64;
  const int quad = lane >> 4, l15 = lane & 15;
  const int sw = l15 & 7;                         // ds_read swizzle key

  const US* Ag[3]  = {A0, A1, A2};
  const US* Wg[3]  = {g.W0, g.W1, g.W2};
  const int ldaS[3] = {lda0, lda1, lda2};
  const int ldwS[3] = {ldw0, ldw1, ldw2};
  const int ktS[3]  = {kt0, kt1, kt2};

  for (int s = 0; s < 3; ++s) {
    const int kt = ktS[s];
    if (kt == 0) continue;
    const int lda = ldaS[s], ldw = ldwS[s];
    const US* ga = Ag[s] + (size_t)(mBase + rowL) * lda + gOff;
    const US* gw = Wg[s] + (size_t)(nBase + rowL) * ldw + gOff;
    const size_t a8 = (size_t)8 * lda, w8 = (size_t)8 * ldw;

    for (int k = 0; k < kt; ++k) {
#pragma unroll
      for (int i = 0; i < 4; i++) {
        __builtin_amdgcn_global_load_lds((AS1 const void*)(ga + i * a8),
                                         (AS3 void*)&As[(w * 32 + i * 8) * 64], 16, 0, 0);
        __builtin_amdgcn_global_load_lds((AS1 const void*)(gw + i * w8),
                                         (AS3 void*)&Bs[(w * 32 + i * 8) * 64], 16, 0, 0);
      }
      __builtin_amdgcn_s_waitcnt(0x0f70);  // vmcnt(0)
      __syncthreads();

#pragma unroll
      for (int ks = 0; ks < 2; ++ks) {
        bf16x8 af[4], bw[4];
#pragma unroll
        for (int i = 0; i < 4; i++)
          af[i] = *(const bf16x8*)&As[(wm + i * 16 + l15) * 64 +
                                      (((ks * 4 + quad) ^ sw) * 8)];
#pragma unroll
        for (int j = 0; j < 4; j++)
          bw[j] = *(const bf16x8*)&Bs[(wn + j * 16 + l15) * 64 +
                                      (((ks * 4 + quad) ^ sw) * 8)];
#pragma unroll
        for (int i = 0; i < 4; i++)
#pragma unroll
          for (int j = 0; j < 4; j++)
            acc[i][j] = __builtin_amdgcn_mfma_f32_16x16x32_bf16(af[i], bw[j], acc[i][j], 0, 0, 0);
      }
      __syncthreads();
      ga += 64; gw += 64;
    }
  }

  // epilogue: row = mBase+wm+i*16+quad*4+r ; col = nBase+wn+j*16+l15
  const int epi = g.epi;
#pragma unroll
  for (int i = 0; i < 4; i++) {
#pragma unroll
    for (int j = 0; j < 4; j++) {
      const int col = nBase + wn + j * 16 + l15;
      const float bv = g.bias[col];
#pragma unroll
      for (int r = 0; r < 4; r++) {
        const int row = mBase + wm + i * 16 + quad * 4 + r;
        float v = acc[i][j][r] + bv;
        if (epi == 0) {
          const float* delta = (const float*)g.aux0;
          const float* wst   = (const float*)g.aux1;
          v += delta[row] * wst[col];
          ((US*)g.outp)[(size_t)row * g.ldo + col] = f2bf(tanh_f(v));
        } else if (epi == 1) {
          const US* hb = (const US*)g.aux0;   // Ab: bf16 h at row*LDA+col
          float rr = sigm(v);
          ((US*)g.outp)[(size_t)row * g.ldo + col] =
              f2bf(rr * bf2f(hb[(size_t)row * LDA + col]));
        } else if (epi == 2) {
          ((US*)g.outp)[(size_t)row * g.ldo + col] = f2bf(sigm(v));
        } else if (epi == 3) {
          ((US*)g.outp)[(size_t)row * g.ldo + col] = f2bf(tanh_f(v));
        } else {
          const US* hb = (const US*)g.aux0;   // Ab: bf16 h
          const US* Zp = (const US*)g.aux1;
          const US* Hp = (const US*)g.aux2;
          float T = sigm(v);
          size_t o = (size_t)row * DH + col;
          float z = bf2f(Zp[o]), ht = bf2f(Hp[o]);
          float h = bf2f(hb[(size_t)row * LDA + col]);
          ((float*)g.outp)[(size_t)row * g.ldo + col] = (1.f - z) * (T * h) + z * ht;
        }
      }
    }
  }
}

extern "C" void kernel_launch(void* const* d_in, const int* in_sizes, int n_in,
                              void* d_out, int out_size, void* d_ws, size_t ws_size,
                              hipStream_t stream) {
  const float* x_t   = (const float*)d_in[0];
  const float* delta = (const float*)d_in[1];
  const float* h_prev= (const float*)d_in[2];
  const float* W_sh  = (const float*)d_in[3];
  const float* W_sx  = (const float*)d_in[4];
  const float* W_st  = (const float*)d_in[5];
  const float* b_s   = (const float*)d_in[6];
  const float* WTh   = (const float*)d_in[7];
  const float* WTx   = (const float*)d_in[8];
  const float* WTs   = (const float*)d_in[9];
  const float* b_T   = (const float*)d_in[10];
  const float* W_rh  = (const float*)d_in[11];
  const float* W_rx  = (const float*)d_in[12];
  const float* b_r   = (const float*)d_in[13];
  const float* W_zh  = (const float*)d_in[14];
  const float* W_zx  = (const float*)d_in[15];
  const float* b_z   = (const float*)d_in[16];
  const float* W_h   = (const float*)d_in[17];
  const float* W_x   = (const float*)d_in[18];
  const float* b_    = (const float*)d_in[19];
  float* out = (float*)d_out;

  char* ws = (char*)d_ws;
  US* Ab = (US*)ws;                         size_t off = (size_t)Bsz * LDA * 2;
  US* RH = (US*)(ws + off);                 off += (size_t)Bsz * DH * 2;
  US* Zb = (US*)(ws + off);                 off += (size_t)Bsz * DH * 2;
  US* HTb = (US*)(ws + off);                off += (size_t)Bsz * DH * 2;
  const size_t WHH = (size_t)DH * DH * 2, WHX = (size_t)DH * DIN * 2;
  US* bWsh = (US*)(ws + off); off += WHH;
  US* bWsx = (US*)(ws + off); off += WHX;
  US* bWTh = (US*)(ws + off); off += WHH;
  US* bWTx = (US*)(ws + off); off += WHX;
  US* bWTs = (US*)(ws + off); off += WHH;
  US* bWrh = (US*)(ws + off); off += WHH;
  US* bWrx = (US*)(ws + off); off += WHX;
  US* bWzh = (US*)(ws + off); off += WHH;
  US* bWzx = (US*)(ws + off); off += WHX;
  US* bWh  = (US*)(ws + off); off += WHH;
  US* bWx  = (US*)(ws + off); off += WHX;

  // Stage 0: convert
  pack_A<<<dim3(8192), 256, 0, stream>>>(h_prev, x_t, Ab);
  WBatch wb;
  const int n4h = DH * DH / 4, n4x = DH * DIN / 4;
  wb.s[0]  = {W_sh, bWsh, n4h};  wb.s[1]  = {W_sx, bWsx, n4x};
  wb.s[2]  = {WTh,  bWTh, n4h};  wb.s[3]  = {WTx,  bWTx, n4x};
  wb.s[4]  = {WTs,  bWTs, n4h};  wb.s[5]  = {W_rh, bWrh, n4h};
  wb.s[6]  = {W_rx, bWrx, n4x};  wb.s[7]  = {W_zh, bWzh, n4h};
  wb.s[8]  = {W_zx, bWzx, n4x};  wb.s[9]  = {W_h,  bWh,  n4h};
  wb.s[10] = {W_x,  bWx,  n4x};
  conv_w<<<dim3(512, 11), 256, 0, stream>>>(wb);

  const US* A_h = Ab;          // K=1024 seg
  const US* A_x = Ab + DH;     // K=512 seg
  const US* A_s = Ab + 1536;   // K=1024 seg (written by gate s)

  // Phase 1: s, r, z fused in one launch (independent, share A)
  GateBatch srz;
  srz.g[0] = {bWsh, bWsx, nullptr, b_s, delta, W_st, nullptr, (void*)A_s, LDA, 0};
  srz.g[1] = {bWrh, bWrx, nullptr, b_r, Ab, nullptr, nullptr, (void*)RH, DH, 1};
  srz.g[2] = {bWzh, bWzx, nullptr, b_z, nullptr, nullptr, nullptr, (void*)Zb, DH, 2};
  gemm_ep<<<dim3(DH / 128, Bsz / 128, 3), 256, 0, stream>>>(
      A_h, LDA, 16, A_x, LDA, 8, nullptr, 0, 0, DH, DIN, 0, srz);

  // Phase 2: h_tilde = tanh([rh|x] @ [W_h|W_x]^T + b)
  GateBatch htb;
  htb.g[0] = {bWh, bWx, nullptr, b_, nullptr, nullptr, nullptr, (void*)HTb, DH, 3};
  gemm_ep<<<dim3(DH / 128, Bsz / 128, 1), 256, 0, stream>>>(
      RH, DH, 16, A_x, LDA, 8, nullptr, 0, 0, DH, DIN, 0, htb);

  // Phase 3: T gate + final combine -> d_out (f32)
  GateBatch tg;
  tg.g[0] = {bWTh, bWTx, bWTs, b_T, Ab, Zb, HTb, (void*)out, DH, 4};
  gemm_ep<<<dim3(DH / 128, Bsz / 128, 1), 256, 0, stream>>>(
      A_h, LDA, 16, A_x, LDA, 8, A_s, LDA, 16, DH, DIN, DH, tg);
}

// Round 4
// 658.772 us; speedup vs baseline: 3.1156x; 3.1156x over previous
//
#include <hip/hip_runtime.h>
#include <stdint.h>

#define AS1 __attribute__((address_space(1)))
#define AS3 __attribute__((address_space(3)))

typedef unsigned short US;
typedef __bf16 bf16x8 __attribute__((ext_vector_type(8)));
typedef float f32x4 __attribute__((ext_vector_type(4)));

static constexpr int Bsz = 16384;
static constexpr int DIN = 512;
static constexpr int DH  = 1024;
static constexpr int LDA = 1536;   // Ab row: [h(1024) | x(512)] — s_t now separate (no aliasing)

__device__ __forceinline__ US f2bf(float f) {
  unsigned u = __float_as_uint(f);
  u += 0x7fffu + ((u >> 16) & 1u);          // RNE
  return (US)(u >> 16);
}
__device__ __forceinline__ float bf2f(US u) { return __uint_as_float(((unsigned)u) << 16); }
__device__ __forceinline__ float sigm(float x) { return 1.f / (1.f + __expf(-x)); }
__device__ __forceinline__ float tanh_f(float x) { return 1.f - 2.f / (1.f + __expf(2.f * x)); }

// ---------- convert kernels ----------
__global__ void pack_A(const float* __restrict__ h, const float* __restrict__ x,
                       US* __restrict__ Ab) {
  const int total = Bsz * 384;              // 1536 cols / 4 per item
  for (int idx = blockIdx.x * blockDim.x + threadIdx.x; idx < total;
       idx += gridDim.x * blockDim.x) {
    int row = idx / 384;
    int c = (idx - row * 384) * 4;
    const float* src = (c < DH) ? (h + (size_t)row * DH + c)
                                : (x + (size_t)row * DIN + (c - DH));
    float4 v = *(const float4*)src;
    ushort4 o;
    o.x = f2bf(v.x); o.y = f2bf(v.y); o.z = f2bf(v.z); o.w = f2bf(v.w);
    *(ushort4*)(Ab + (size_t)row * LDA + c) = o;
  }
}

struct WSlot { const float* src; US* dst; int n4; };
struct WBatch { WSlot s[11]; };
__global__ void conv_w(WBatch b) {
  WSlot sl = b.s[blockIdx.y];   // uniform per block — SGPR-resolved, no scratch
  for (int i = blockIdx.x * blockDim.x + threadIdx.x; i < sl.n4;
       i += gridDim.x * blockDim.x) {
    float4 v = *(const float4*)(sl.src + (size_t)i * 4);
    ushort4 o;
    o.x = f2bf(v.x); o.y = f2bf(v.y); o.z = f2bf(v.z); o.w = f2bf(v.w);
    *(ushort4*)(sl.dst + (size_t)i * 4) = o;
  }
}

// ---------- segmented-K GEMM, C = A @ W^T, fused epilogue ----------
// Compile-time segment counts (R2 lesson: runtime-indexed locals -> scratch spill).
// Alias-free dataflow (R3 lesson: no dispatch writes a buffer it also reads).
// EPI: 0=s(tanh,+delta*Wst ->Sb bf16)  1=r(sigm*h_prev ->RH bf16)
//      2=z(sigm ->Z bf16)  3=htilde(tanh ->HT bf16)
//      4=T(sigm; h_t=(1-z)(T*h)+z*ht ->f32 out)
template <int EPI, int KT0, int KT1, int KT2>
__global__ __launch_bounds__(256) void gemm_ep(
    const US* __restrict__ A0, int lda0,
    const US* __restrict__ A1, int lda1,
    const US* __restrict__ A2, int lda2,
    const US* __restrict__ W0, int ldw0,
    const US* __restrict__ W1, int ldw1,
    const US* __restrict__ W2, int ldw2,
    const float* __restrict__ bias,
    const void* aux0, const void* aux1, const void* aux2,
    void* outp, int ldo) {
  __shared__ __align__(16) US As[128 * 64];
  __shared__ __align__(16) US Bs[128 * 64];

  const int tid  = threadIdx.x;
  const int lane = tid & 63;
  const int w    = tid >> 6;
  const int mBase = blockIdx.y * 128;
  const int nBase = blockIdx.x * 128;

  f32x4 acc[4][4];
#pragma unroll
  for (int i = 0; i < 4; i++)
#pragma unroll
    for (int j = 0; j < 4; j++) acc[i][j] = f32x4{0.f, 0.f, 0.f, 0.f};

  // XOR swizzle: LDS(m, cc) holds global(m, cc ^ (m&7)) -> conflict-free ds_read
  // (verified R2: SQ_LDS_BANK_CONFLICT == 0) while global staging stays coalesced.
  const int rowL = w * 32 + (lane >> 3);
  const int cc   = lane & 7;
  const int scc  = cc ^ ((lane >> 3) & 7);
  const int gOff = scc * 8;
  const int wm = (w & 1) * 64, wn = (w >> 1) * 64;
  const int quad = lane >> 4, l15 = lane & 15;
  const int sw = l15 & 7;

#define K_TILE_LOOP(Ap, lda, Wp, ldw, KT)                                          \
  {                                                                                \
    const US* ga = (Ap) + (size_t)(mBase + rowL) * (lda) + gOff;                   \
    const US* gw = (Wp) + (size_t)(nBase + rowL) * (ldw) + gOff;                   \
    const size_t a8 = (size_t)8 * (lda), w8 = (size_t)8 * (ldw);                   \
    for (int k = 0; k < (KT); ++k) {                                               \
      _Pragma("unroll")                                                            \
      for (int i = 0; i < 4; i++) {                                                \
        __builtin_amdgcn_global_load_lds((AS1 const void*)(ga + i * a8),           \
            (AS3 void*)&As[(w * 32 + i * 8) * 64], 16, 0, 0);                      \
        __builtin_amdgcn_global_load_lds((AS1 const void*)(gw + i * w8),           \
            (AS3 void*)&Bs[(w * 32 + i * 8) * 64], 16, 0, 0);                      \
      }                                                                            \
      __builtin_amdgcn_s_waitcnt(0x0f70);                                          \
      __syncthreads();                                                             \
      _Pragma("unroll")                                                            \
      for (int ks = 0; ks < 2; ++ks) {                                             \
        bf16x8 af[4], bw[4];                                                       \
        _Pragma("unroll")                                                          \
        for (int i = 0; i < 4; i++)                                                \
          af[i] = *(const bf16x8*)&As[(wm + i * 16 + l15) * 64 +                   \
                                      (((ks * 4 + quad) ^ sw) * 8)];               \
        _Pragma("unroll")                                                          \
        for (int j = 0; j < 4; j++)                                                \
          bw[j] = *(const bf16x8*)&Bs[(wn + j * 16 + l15) * 64 +                   \
                                      (((ks * 4 + quad) ^ sw) * 8)];               \
        _Pragma("unroll")                                                          \
        for (int i = 0; i < 4; i++)                                                \
          _Pragma("unroll")                                                        \
          for (int j = 0; j < 4; j++)                                              \
            acc[i][j] = __builtin_amdgcn_mfma_f32_16x16x32_bf16(af[i], bw[j],      \
                                                                acc[i][j], 0, 0, 0);\
      }                                                                            \
      __syncthreads();                                                             \
      ga += 64; gw += 64;                                                          \
    }                                                                              \
  }

  if constexpr (KT0 > 0) K_TILE_LOOP(A0, lda0, W0, ldw0, KT0);
  if constexpr (KT1 > 0) K_TILE_LOOP(A1, lda1, W1, ldw1, KT1);
  if constexpr (KT2 > 0) K_TILE_LOOP(A2, lda2, W2, ldw2, KT2);
#undef K_TILE_LOOP

  // epilogue: row = mBase+wm+i*16+quad*4+r ; col = nBase+wn+j*16+l15
#pragma unroll
  for (int i = 0; i < 4; i++) {
#pragma unroll
    for (int j = 0; j < 4; j++) {
      const int col = nBase + wn + j * 16 + l15;
      const float bv = bias[col];
#pragma unroll
      for (int r = 0; r < 4; r++) {
        const int row = mBase + wm + i * 16 + quad * 4 + r;
        float v = acc[i][j][r] + bv;
        if constexpr (EPI == 0) {
          const float* delta = (const float*)aux0;
          const float* wst   = (const float*)aux1;
          v += delta[row] * wst[col];
          ((US*)outp)[(size_t)row * ldo + col] = f2bf(tanh_f(v));
        } else if constexpr (EPI == 1) {
          const float* hp = (const float*)aux0;   // pristine f32 h_prev
          float rr = sigm(v);
          ((US*)outp)[(size_t)row * ldo + col] =
              f2bf(rr * hp[(size_t)row * DH + col]);
        } else if constexpr (EPI == 2) {
          ((US*)outp)[(size_t)row * ldo + col] = f2bf(sigm(v));
        } else if constexpr (EPI == 3) {
          ((US*)outp)[(size_t)row * ldo + col] = f2bf(tanh_f(v));
        } else {
          const float* hp = (const float*)aux0;   // pristine f32 h_prev
          const US* Zp = (const US*)aux1;
          const US* Hp = (const US*)aux2;
          float T = sigm(v);
          size_t o = (size_t)row * DH + col;
          float z = bf2f(Zp[o]), ht = bf2f(Hp[o]);
          float h = hp[o];
          ((float*)outp)[(size_t)row * ldo + col] = (1.f - z) * (T * h) + z * ht;
        }
      }
    }
  }
}

extern "C" void kernel_launch(void* const* d_in, const int* in_sizes, int n_in,
                              void* d_out, int out_size, void* d_ws, size_t ws_size,
                              hipStream_t stream) {
  const float* x_t   = (const float*)d_in[0];
  const float* delta = (const float*)d_in[1];
  const float* h_prev= (const float*)d_in[2];
  const float* W_sh  = (const float*)d_in[3];
  const float* W_sx  = (const float*)d_in[4];
  const float* W_st  = (const float*)d_in[5];
  const float* b_s   = (const float*)d_in[6];
  const float* WTh   = (const float*)d_in[7];
  const float* WTx   = (const float*)d_in[8];
  const float* WTs   = (const float*)d_in[9];
  const float* b_T   = (const float*)d_in[10];
  const float* W_rh  = (const float*)d_in[11];
  const float* W_rx  = (const float*)d_in[12];
  const float* b_r   = (const float*)d_in[13];
  const float* W_zh  = (const float*)d_in[14];
  const float* W_zx  = (const float*)d_in[15];
  const float* b_z   = (const float*)d_in[16];
  const float* W_h   = (const float*)d_in[17];
  const float* W_x   = (const float*)d_in[18];
  const float* b_    = (const float*)d_in[19];
  float* out = (float*)d_out;

  char* ws = (char*)d_ws;
  US* Ab = (US*)ws;                         size_t off = (size_t)Bsz * LDA * 2;
  US* Sb = (US*)(ws + off);                 off += (size_t)Bsz * DH * 2;
  US* RH = (US*)(ws + off);                 off += (size_t)Bsz * DH * 2;
  US* Zb = (US*)(ws + off);                 off += (size_t)Bsz * DH * 2;
  US* HTb = (US*)(ws + off);                off += (size_t)Bsz * DH * 2;
  const size_t WHH = (size_t)DH * DH * 2, WHX = (size_t)DH * DIN * 2;
  US* bWsh = (US*)(ws + off); off += WHH;
  US* bWsx = (US*)(ws + off); off += WHX;
  US* bWTh = (US*)(ws + off); off += WHH;
  US* bWTx = (US*)(ws + off); off += WHX;
  US* bWTs = (US*)(ws + off); off += WHH;
  US* bWrh = (US*)(ws + off); off += WHH;
  US* bWrx = (US*)(ws + off); off += WHX;
  US* bWzh = (US*)(ws + off); off += WHH;
  US* bWzx = (US*)(ws + off); off += WHX;
  US* bWh  = (US*)(ws + off); off += WHH;
  US* bWx  = (US*)(ws + off); off += WHX;

  // Stage 0: convert
  pack_A<<<dim3(8192), 256, 0, stream>>>(h_prev, x_t, Ab);
  WBatch wb;
  const int n4h = DH * DH / 4, n4x = DH * DIN / 4;
  wb.s[0]  = {W_sh, bWsh, n4h};  wb.s[1]  = {W_sx, bWsx, n4x};
  wb.s[2]  = {WTh,  bWTh, n4h};  wb.s[3]  = {WTx,  bWTx, n4x};
  wb.s[4]  = {WTs,  bWTs, n4h};  wb.s[5]  = {W_rh, bWrh, n4h};
  wb.s[6]  = {W_rx, bWrx, n4x};  wb.s[7]  = {W_zh, bWzh, n4h};
  wb.s[8]  = {W_zx, bWzx, n4x};  wb.s[9]  = {W_h,  bWh,  n4h};
  wb.s[10] = {W_x,  bWx,  n4x};
  conv_w<<<dim3(512, 11), 256, 0, stream>>>(wb);

  dim3 grid(DH / 128, Bsz / 128);  // (8, 128)
  const US* A_h = Ab;          // K=1024 seg
  const US* A_x = Ab + DH;     // K=512 seg

  // Phase 1: s, r, z  (all read only Ab/d_in; write disjoint private buffers)
  gemm_ep<0, 16, 8, 0><<<grid, 256, 0, stream>>>(
      A_h, LDA, A_x, LDA, nullptr, 0,
      bWsh, DH, bWsx, DIN, nullptr, 0,
      b_s, delta, W_st, nullptr, (void*)Sb, DH);
  gemm_ep<1, 16, 8, 0><<<grid, 256, 0, stream>>>(
      A_h, LDA, A_x, LDA, nullptr, 0,
      bWrh, DH, bWrx, DIN, nullptr, 0,
      b_r, h_prev, nullptr, nullptr, (void*)RH, DH);
  gemm_ep<2, 16, 8, 0><<<grid, 256, 0, stream>>>(
      A_h, LDA, A_x, LDA, nullptr, 0,
      bWzh, DH, bWzx, DIN, nullptr, 0,
      b_z, nullptr, nullptr, nullptr, (void*)Zb, DH);
  // Phase 2: h_tilde = tanh([rh|x] @ [W_h|W_x]^T + b)
  gemm_ep<3, 16, 8, 0><<<grid, 256, 0, stream>>>(
      RH, DH, A_x, LDA, nullptr, 0,
      bWh, DH, bWx, DIN, nullptr, 0,
      b_, nullptr, nullptr, nullptr, (void*)HTb, DH);
  // Phase 3: T gate + final combine -> d_out (f32)
  gemm_ep<4, 16, 8, 16><<<grid, 256, 0, stream>>>(
      A_h, LDA, A_x, LDA, Sb, DH,
      bWTh, DH, bWTx, DIN, bWTs, DH,
      b_T, h_prev, Zb, HTb, (void*)out, DH);
}

// Round 5
// 655.756 us; speedup vs baseline: 3.1299x; 1.0046x over previous
//
#include <hip/hip_runtime.h>
#include <stdint.h>

#define AS1 __attribute__((address_space(1)))
#define AS3 __attribute__((address_space(3)))

typedef unsigned short US;
typedef __bf16 bf16x8 __attribute__((ext_vector_type(8)));
typedef float f32x4 __attribute__((ext_vector_type(4)));

static constexpr int Bsz = 16384;
static constexpr int DIN = 512;
static constexpr int DH  = 1024;
static constexpr int LDA = 1536;   // Ab row: [h(1024) | x(512)] — s_t separate (no aliasing)

__device__ __forceinline__ US f2bf(float f) {
  unsigned u = __float_as_uint(f);
  u += 0x7fffu + ((u >> 16) & 1u);          // RNE
  return (US)(u >> 16);
}
__device__ __forceinline__ float bf2f(US u) { return __uint_as_float(((unsigned)u) << 16); }
__device__ __forceinline__ float sigm(float x) { return 1.f / (1.f + __expf(-x)); }
__device__ __forceinline__ float tanh_f(float x) { return 1.f - 2.f / (1.f + __expf(2.f * x)); }

// ---------- convert kernels ----------
__global__ void pack_A(const float* __restrict__ h, const float* __restrict__ x,
                       US* __restrict__ Ab) {
  const int total = Bsz * 384;              // 1536 cols / 4 per item
  for (int idx = blockIdx.x * blockDim.x + threadIdx.x; idx < total;
       idx += gridDim.x * blockDim.x) {
    int row = idx / 384;
    int c = (idx - row * 384) * 4;
    const float* src = (c < DH) ? (h + (size_t)row * DH + c)
                                : (x + (size_t)row * DIN + (c - DH));
    float4 v = *(const float4*)src;
    ushort4 o;
    o.x = f2bf(v.x); o.y = f2bf(v.y); o.z = f2bf(v.z); o.w = f2bf(v.w);
    *(ushort4*)(Ab + (size_t)row * LDA + c) = o;
  }
}

struct WSlot { const float* src; US* dst; int n4; };
struct WBatch { WSlot s[11]; };
__global__ void conv_w(WBatch b) {
  WSlot sl = b.s[blockIdx.y];   // uniform per block — SGPR-resolved, no scratch
  for (int i = blockIdx.x * blockDim.x + threadIdx.x; i < sl.n4;
       i += gridDim.x * blockDim.x) {
    float4 v = *(const float4*)(sl.src + (size_t)i * 4);
    ushort4 o;
    o.x = f2bf(v.x); o.y = f2bf(v.y); o.z = f2bf(v.z); o.w = f2bf(v.w);
    *(ushort4*)(sl.dst + (size_t)i * 4) = o;
  }
}

// ---------- segmented-K GEMM, C = A @ W^T, fused epilogue ----------
// Compile-time segment counts (R2 lesson: runtime-indexed locals -> scratch spill).
// Alias-free dataflow (R3 lesson: no dispatch writes a buffer it also reads).
// XCD-aware block swizzle (R4 lesson: default round-robin puts the 8 n-peers of
// one A row-block on 8 different XCD L2s -> whole-A fetch per XCD, 4.5x over-fetch).
// EPI: 0=s(tanh,+delta*Wst ->Sb bf16)  1=r(sigm*h_prev ->RH bf16)
//      2=z(sigm ->Z bf16)  3=htilde(tanh ->HT bf16)
//      4=T(sigm; h_t=(1-z)(T*h)+z*ht ->f32 out)
template <int EPI, int KT0, int KT1, int KT2>
__global__ __launch_bounds__(256) void gemm_ep(
    const US* __restrict__ A0, int lda0,
    const US* __restrict__ A1, int lda1,
    const US* __restrict__ A2, int lda2,
    const US* __restrict__ W0, int ldw0,
    const US* __restrict__ W1, int ldw1,
    const US* __restrict__ W2, int ldw2,
    const float* __restrict__ bias,
    const void* aux0, const void* aux1, const void* aux2,
    void* outp, int ldo) {
  __shared__ __align__(16) US As[128 * 64];
  __shared__ __align__(16) US Bs[128 * 64];

  const int tid  = threadIdx.x;
  const int lane = tid & 63;
  const int w    = tid >> 6;

  // XCD-aware swizzle: p%8 tracks the XCD round-robin. XCD c owns m-slab
  // [c*16, c*16+16); within a slab, n varies fastest so the 8 n-peers of an
  // m-block are co-resident on one XCD -> A row-block hits that XCD's L2.
  const int p = blockIdx.x + (int)(gridDim.x * blockIdx.y);
  const int c = p & 7;
  const int q = p >> 3;
  const int nIdx = q & 7;                 // gridDim.x == 8
  const int mIdx = c * 16 + (q >> 3);     // gridDim.y == 128 -> 16 m-blocks/XCD
  const int mBase = mIdx * 128;
  const int nBase = nIdx * 128;

  f32x4 acc[4][4];
#pragma unroll
  for (int i = 0; i < 4; i++)
#pragma unroll
    for (int j = 0; j < 4; j++) acc[i][j] = f32x4{0.f, 0.f, 0.f, 0.f};

  // XOR swizzle: LDS(m, cc) holds global(m, cc ^ (m&7)) -> conflict-free ds_read
  // (verified R2/R4: SQ_LDS_BANK_CONFLICT == 0), global staging stays coalesced.
  const int rowL = w * 32 + (lane >> 3);
  const int cc   = lane & 7;
  const int scc  = cc ^ ((lane >> 3) & 7);
  const int gOff = scc * 8;
  const int wm = (w & 1) * 64, wn = (w >> 1) * 64;
  const int quad = lane >> 4, l15 = lane & 15;
  const int sw = l15 & 7;

#define K_TILE_LOOP(Ap, lda, Wp, ldw, KT)                                          \
  {                                                                                \
    const US* ga = (Ap) + (size_t)(mBase + rowL) * (lda) + gOff;                   \
    const US* gw = (Wp) + (size_t)(nBase + rowL) * (ldw) + gOff;                   \
    const size_t a8 = (size_t)8 * (lda), w8 = (size_t)8 * (ldw);                   \
    for (int k = 0; k < (KT); ++k) {                                               \
      _Pragma("unroll")                                                            \
      for (int i = 0; i < 4; i++) {                                                \
        __builtin_amdgcn_global_load_lds((AS1 const void*)(ga + i * a8),           \
            (AS3 void*)&As[(w * 32 + i * 8) * 64], 16, 0, 0);                      \
        __builtin_amdgcn_global_load_lds((AS1 const void*)(gw + i * w8),           \
            (AS3 void*)&Bs[(w * 32 + i * 8) * 64], 16, 0, 0);                      \
      }                                                                            \
      __builtin_amdgcn_s_waitcnt(0x0f70);                                          \
      __syncthreads();                                                             \
      _Pragma("unroll")                                                            \
      for (int ks = 0; ks < 2; ++ks) {                                             \
        bf16x8 af[4], bw[4];                                                       \
        _Pragma("unroll")                                                          \
        for (int i = 0; i < 4; i++)                                                \
          af[i] = *(const bf16x8*)&As[(wm + i * 16 + l15) * 64 +                   \
                                      (((ks * 4 + quad) ^ sw) * 8)];               \
        _Pragma("unroll")                                                          \
        for (int j = 0; j < 4; j++)                                                \
          bw[j] = *(const bf16x8*)&Bs[(wn + j * 16 + l15) * 64 +                   \
                                      (((ks * 4 + quad) ^ sw) * 8)];               \
        _Pragma("unroll")                                                          \
        for (int i = 0; i < 4; i++)                                                \
          _Pragma("unroll")                                                        \
          for (int j = 0; j < 4; j++)                                              \
            acc[i][j] = __builtin_amdgcn_mfma_f32_16x16x32_bf16(af[i], bw[j],      \
                                                                acc[i][j], 0, 0, 0);\
      }                                                                            \
      __syncthreads();                                                             \
      ga += 64; gw += 64;                                                          \
    }                                                                              \
  }

  if constexpr (KT0 > 0) K_TILE_LOOP(A0, lda0, W0, ldw0, KT0);
  if constexpr (KT1 > 0) K_TILE_LOOP(A1, lda1, W1, ldw1, KT1);
  if constexpr (KT2 > 0) K_TILE_LOOP(A2, lda2, W2, ldw2, KT2);
#undef K_TILE_LOOP

  // epilogue: row = mBase+wm+i*16+quad*4+r ; col = nBase+wn+j*16+l15
#pragma unroll
  for (int i = 0; i < 4; i++) {
#pragma unroll
    for (int j = 0; j < 4; j++) {
      const int col = nBase + wn + j * 16 + l15;
      const float bv = bias[col];
#pragma unroll
      for (int r = 0; r < 4; r++) {
        const int row = mBase + wm + i * 16 + quad * 4 + r;
        float v = acc[i][j][r] + bv;
        if constexpr (EPI == 0) {
          const float* delta = (const float*)aux0;
          const float* wst   = (const float*)aux1;
          v += delta[row] * wst[col];
          ((US*)outp)[(size_t)row * ldo + col] = f2bf(tanh_f(v));
        } else if constexpr (EPI == 1) {
          const float* hp = (const float*)aux0;   // pristine f32 h_prev
          float rr = sigm(v);
          ((US*)outp)[(size_t)row * ldo + col] =
              f2bf(rr * hp[(size_t)row * DH + col]);
        } else if constexpr (EPI == 2) {
          ((US*)outp)[(size_t)row * ldo + col] = f2bf(sigm(v));
        } else if constexpr (EPI == 3) {
          ((US*)outp)[(size_t)row * ldo + col] = f2bf(tanh_f(v));
        } else {
          const float* hp = (const float*)aux0;   // pristine f32 h_prev
          const US* Zp = (const US*)aux1;
          const US* Hp = (const US*)aux2;
          float T = sigm(v);
          size_t o = (size_t)row * DH + col;
          float z = bf2f(Zp[o]), ht = bf2f(Hp[o]);
          float h = hp[o];
          ((float*)outp)[(size_t)row * ldo + col] = (1.f - z) * (T * h) + z * ht;
        }
      }
    }
  }
}

extern "C" void kernel_launch(void* const* d_in, const int* in_sizes, int n_in,
                              void* d_out, int out_size, void* d_ws, size_t ws_size,
                              hipStream_t stream) {
  const float* x_t   = (const float*)d_in[0];
  const float* delta = (const float*)d_in[1];
  const float* h_prev= (const float*)d_in[2];
  const float* W_sh  = (const float*)d_in[3];
  const float* W_sx  = (const float*)d_in[4];
  const float* W_st  = (const float*)d_in[5];
  const float* b_s   = (const float*)d_in[6];
  const float* WTh   = (const float*)d_in[7];
  const float* WTx   = (const float*)d_in[8];
  const float* WTs   = (const float*)d_in[9];
  const float* b_T   = (const float*)d_in[10];
  const float* W_rh  = (const float*)d_in[11];
  const float* W_rx  = (const float*)d_in[12];
  const float* b_r   = (const float*)d_in[13];
  const float* W_zh  = (const float*)d_in[14];
  const float* W_zx  = (const float*)d_in[15];
  const float* b_z   = (const float*)d_in[16];
  const float* W_h   = (const float*)d_in[17];
  const float* W_x   = (const float*)d_in[18];
  const float* b_    = (const float*)d_in[19];
  float* out = (float*)d_out;

  char* ws = (char*)d_ws;
  US* Ab = (US*)ws;                         size_t off = (size_t)Bsz * LDA * 2;
  US* Sb = (US*)(ws + off);                 off += (size_t)Bsz * DH * 2;
  US* RH = (US*)(ws + off);                 off += (size_t)Bsz * DH * 2;
  US* Zb = (US*)(ws + off);                 off += (size_t)Bsz * DH * 2;
  US* HTb = (US*)(ws + off);                off += (size_t)Bsz * DH * 2;
  const size_t WHH = (size_t)DH * DH * 2, WHX = (size_t)DH * DIN * 2;
  US* bWsh = (US*)(ws + off); off += WHH;
  US* bWsx = (US*)(ws + off); off += WHX;
  US* bWTh = (US*)(ws + off); off += WHH;
  US* bWTx = (US*)(ws + off); off += WHX;
  US* bWTs = (US*)(ws + off); off += WHH;
  US* bWrh = (US*)(ws + off); off += WHH;
  US* bWrx = (US*)(ws + off); off += WHX;
  US* bWzh = (US*)(ws + off); off += WHH;
  US* bWzx = (US*)(ws + off); off += WHX;
  US* bWh  = (US*)(ws + off); off += WHH;
  US* bWx  = (US*)(ws + off); off += WHX;

  // Stage 0: convert
  pack_A<<<dim3(8192), 256, 0, stream>>>(h_prev, x_t, Ab);
  WBatch wb;
  const int n4h = DH * DH / 4, n4x = DH * DIN / 4;
  wb.s[0]  = {W_sh, bWsh, n4h};  wb.s[1]  = {W_sx, bWsx, n4x};
  wb.s[2]  = {WTh,  bWTh, n4h};  wb.s[3]  = {WTx,  bWTx, n4x};
  wb.s[4]  = {WTs,  bWTs, n4h};  wb.s[5]  = {W_rh, bWrh, n4h};
  wb.s[6]  = {W_rx, bWrx, n4x};  wb.s[7]  = {W_zh, bWzh, n4h};
  wb.s[8]  = {W_zx, bWzx, n4x};  wb.s[9]  = {W_h,  bWh,  n4h};
  wb.s[10] = {W_x,  bWx,  n4x};
  conv_w<<<dim3(512, 11), 256, 0, stream>>>(wb);

  dim3 grid(DH / 128, Bsz / 128);  // (8, 128)
  const US* A_h = Ab;          // K=1024 seg
  const US* A_x = Ab + DH;     // K=512 seg

  // Phase 1: s, r, z  (all read only Ab/d_in; write disjoint private buffers)
  gemm_ep<0, 16, 8, 0><<<grid, 256, 0, stream>>>(
      A_h, LDA, A_x, LDA, nullptr, 0,
      bWsh, DH, bWsx, DIN, nullptr, 0,
      b_s, delta, W_st, nullptr, (void*)Sb, DH);
  gemm_ep<1, 16, 8, 0><<<grid, 256, 0, stream>>>(
      A_h, LDA, A_x, LDA, nullptr, 0,
      bWrh, DH, bWrx, DIN, nullptr, 0,
      b_r, h_prev, nullptr, nullptr, (void*)RH, DH);
  gemm_ep<2, 16, 8, 0><<<grid, 256, 0, stream>>>(
      A_h, LDA, A_x, LDA, nullptr, 0,
      bWzh, DH, bWzx, DIN, nullptr, 0,
      b_z, nullptr, nullptr, nullptr, (void*)Zb, DH);
  // Phase 2: h_tilde = tanh([rh|x] @ [W_h|W_x]^T + b)
  gemm_ep<3, 16, 8, 0><<<grid, 256, 0, stream>>>(
      RH, DH, A_x, LDA, nullptr, 0,
      bWh, DH, bWx, DIN, nullptr, 0,
      b_, nullptr, nullptr, nullptr, (void*)HTb, DH);
  // Phase 3: T gate + final combine -> d_out (f32)
  gemm_ep<4, 16, 8, 16><<<grid, 256, 0, stream>>>(
      A_h, LDA, A_x, LDA, Sb, DH,
      bWTh, DH, bWTx, DIN, bWTs, DH,
      b_T, h_prev, Zb, HTb, (void*)out, DH);
}